// Round 8
// baseline (344.171 us; speedup 1.0000x reference)
//
#include <hip/hip_runtime.h>
#include <hip/hip_bf16.h>

typedef unsigned int u32;
typedef unsigned short u16;
typedef short short8 __attribute__((ext_vector_type(8)));
typedef float f32x4 __attribute__((ext_vector_type(4)));
typedef float f32x16 __attribute__((ext_vector_type(16)));

#define R_ 32
#define KEYS_PER_B 2048     // 32 relations * 64 rows per batch
#define SORT_STRIDE 1024    // fixed per-chunk slots in sorted[] (mean 767, +9 sigma)

static __device__ __forceinline__ u16 f2bf(float f) {
  u32 u = __float_as_uint(f);
  u = (u + 0x7FFFu + ((u >> 16) & 1u)) >> 16;   // RNE
  return (u16)u;
}
static __device__ __forceinline__ u32 pk2(float a, float b) {
  __hip_bfloat162 h2 = __float22bfloat162_rn(make_float2(a, b));
  union { __hip_bfloat162 h; u32 u; } cv; cv.h = h2; return cv.u;
}

static __device__ __forceinline__ int sort_key(int tgt, int r) {
  return (tgt >> 6) * KEYS_PER_B + r * 64 + (tgt & 63);
}

// ---- fused: x fp32->bf16 convert + W/W_root pack (32x32x16 B-frag order) + hist ----
// wp frame (rr*4+ct)*8+ks holds B[k][n]: n = ct*32 + (lane&31), k = ks*16 + (lane>>5)*8 + j
__global__ void k_pre(const float* __restrict__ x, const float* __restrict__ W,
                      const float* __restrict__ Wroot, const int* __restrict__ ei,
                      const int* __restrict__ et, u16* __restrict__ xb,
                      u16* __restrict__ wp, int* __restrict__ hist,
                      int n4, int E, int convNB, int packNB) {
  const int bb = (int)blockIdx.x;
  if (bb < convNB) {
    int i = bb * 256 + threadIdx.x;
    if (i >= n4) return;
    const float4 f = ((const float4*)x)[i];
    u32 lo = (u32)f2bf(f.x) | ((u32)f2bf(f.y) << 16);
    u32 hi = (u32)f2bf(f.z) | ((u32)f2bf(f.w) << 16);
    ((uint2*)xb)[i] = make_uint2(lo, hi);
  } else if (bb < convNB + packNB) {
    int tid = (bb - convNB) * 256 + threadIdx.x;
    if (tid >= 33 * 2048) return;
    int lane = tid & 63;
    int ks = (tid >> 6) & 7;
    int ct = (tid >> 9) & 3;
    int rr = tid >> 11;
    int i0 = ks * 16 + (lane >> 5) * 8;
    int o  = ct * 32 + (lane & 31);
    const float* src = (rr < 32) ? (W + (size_t)rr * (128 * 128)) : Wroot;
    u16* dst = wp + ((size_t)((rr * 4 + ct) * 8 + ks) * 64 + lane) * 8;
#pragma unroll
    for (int j = 0; j < 8; ++j) dst[j] = f2bf(src[(size_t)(i0 + j) * 128 + o]);
  } else {
    int e4 = ((bb - convNB - packNB) * 256 + threadIdx.x) * 4;
    if (e4 >= E) return;
    const int4 tg = *(const int4*)(ei + E + e4);
    const int4 rt = *(const int4*)(et + e4);
    atomicAdd(hist + sort_key(tg.x, rt.x), 1);
    atomicAdd(hist + sort_key(tg.y, rt.y), 1);
    atomicAdd(hist + sort_key(tg.z, rt.z), 1);
    atomicAdd(hist + sort_key(tg.w, rt.w), 1);
  }
}

// ---- per-chunk exclusive scan (chunk = 2048 keys = one batch) ----
__global__ __launch_bounds__(256) void k_scan_local(const int* __restrict__ hist,
                                                    int* __restrict__ offs) {
  __shared__ int wsum[4];
  int b = blockIdx.x, t = threadIdx.x;
  size_t base = (size_t)b * KEYS_PER_B + (size_t)t * 8;
  int4 a = *(const int4*)(hist + base);
  int4 c = *(const int4*)(hist + base + 4);
  int v[8] = {a.x, a.y, a.z, a.w, c.x, c.y, c.z, c.w};
  int s = 0;
#pragma unroll
  for (int i = 0; i < 8; ++i) s += v[i];
  int lane = t & 63, w = t >> 6;
  int x = s;
#pragma unroll
  for (int off = 1; off < 64; off <<= 1) {
    int y = __shfl_up(x, off);
    if (lane >= off) x += y;
  }
  if (lane == 63) wsum[w] = x;
  __syncthreads();
  int wb = 0;
  for (int i = 0; i < w; ++i) wb += wsum[i];
  int ex = wb + x - s;
  int o[8];
#pragma unroll
  for (int i = 0; i < 8; ++i) { o[i] = ex; ex += v[i]; }
  *(int4*)(offs + base) = make_int4(o[0], o[1], o[2], o[3]);
  *(int4*)(offs + base + 4) = make_int4(o[4], o[5], o[6], o[7]);
}

// ---- scatter (4 edges/thread); offs[key] becomes per-key chunk-local END ----
__global__ void k_scatter(const int* __restrict__ ei, const int* __restrict__ et,
                          int* __restrict__ offs, u32* __restrict__ sorted, int E) {
  int e4 = (blockIdx.x * 256 + threadIdx.x) * 4;
  if (e4 >= E) return;
  const int4 sr = *(const int4*)(ei + e4);
  const int4 tg = *(const int4*)(ei + E + e4);
  const int4 rt = *(const int4*)(et + e4);
#pragma unroll
  for (int j = 0; j < 4; ++j) {
    int src = (&sr.x)[j], tgt = (&tg.x)[j], r = (&rt.x)[j];
    int p = atomicAdd(offs + sort_key(tgt, r), 1);
    if (p < SORT_STRIDE)
      sorted[(size_t)(tgt >> 6) * SORT_STRIDE + p] = (u32)src | ((u32)(tgt & 63) << 16);
  }
}

// ---- main batch kernel: MFMA aggregation P@(Xg@W), column-split waves ----
// Wave w owns output cols w*32..w*32+31 for all 64 rows (acc = 32 VGPR only).
// All waves process every relation. Per 32-edge chunk:
//   P (64x32 bf16, LDS): zero + one ds_write_b16 per edge (1/cnt at row tl)
//   Z = Xg @ W[:,ct]  (A-frags = per-lane 16B edge gathers; 8 MFMAs)
//   Zt: Z C-layout -> [col][edge] LDS (wave-private)
//   acc += P @ Z  (A-frags from P-LDS, B-frags from Zt; 4 MFMAs)
// Zero barriers; wave-private LDS only; direct column stores in epilogue.
__global__ __launch_bounds__(256, 2) void k_batch(
    const u16* __restrict__ xb, const u16* __restrict__ wp,
    const float* __restrict__ bias, const u32* __restrict__ sorted,
    const int* __restrict__ offs, float* __restrict__ h, int N) {
  __shared__ u16 smem[4 * 3840];   // per wave: P 64x40 (2560) + Zt 32x40 (1280)
  const int b = blockIdx.x, t = threadIdx.x;
  const int lane = t & 63, w = t >> 6;
  const int l31 = lane & 31, lh = lane >> 5;
  const int nb = b * 64;
  const int keyBase = b * KEYS_PER_B;
  const u32* srt = sorted + (size_t)b * SORT_STRIDE;
  u16* myP  = smem + w * 3840;
  u16* myZt = smem + w * 3840 + 2560;
  const short8 zero8 = {0, 0, 0, 0, 0, 0, 0, 0};

  // lane r (r<32) holds end of relation r's segment (chunk-local)
  const int relEnd = offs[keyBase + (lane & 31) * 64 + 63];
  int sSeg = 0;
  int eSeg = __builtin_amdgcn_readlane(relEnd, 0);

  // relation-0 window + per-lane (tl, 1/cnt) + chunk-0 A-gathers
  u32 ev = srt[lane];
  int tlv = (int)((ev >> 16) & 63);
  u32 normu;
  {
    int L = tlv;                               // r = 0
    int cE = offs[keyBase + L];
    int cS = (L > 0) ? offs[keyBase + L - 1] : 0;
    normu = (lane < eSeg - sSeg) ? (u32)f2bf(1.0f / (float)(cE - cS)) : 0u;
  }
  short8 A0[8];
  {
    u32 srn = (u32)__shfl((int)ev, l31) & 0xFFFFu;
    const u16* xp = xb + (size_t)srn * 128 + lh * 8;
#pragma unroll
    for (int ks = 0; ks < 8; ++ks) A0[ks] = *(const short8*)(xp + ks * 16);
  }

  f32x16 acc0, acc1;
#pragma unroll
  for (int k = 0; k < 16; ++k) { acc0[k] = 0.f; acc1[k] = 0.f; }

  // ---- root GEMM: acc += X[64x128] @ Wroot[:, w*32..] ----
  {
    const u16* wrr = wp + (size_t)((32 * 4 + w) * 8) * 64 * 8;
    short8 wfr[8];
#pragma unroll
    for (int ks = 0; ks < 8; ++ks)
      wfr[ks] = *(const short8*)(wrr + ((size_t)ks * 64 + lane) * 8);
#pragma unroll
    for (int mt = 0; mt < 2; ++mt) {
      const int node = nb + mt * 32 + l31;
      const u16* xp = xb + (size_t)node * 128 + lh * 8;
#pragma unroll
      for (int ks = 0; ks < 8; ++ks) {
        short8 a = (node < N) ? *(const short8*)(xp + ks * 16) : zero8;
        if (mt == 0) acc0 = __builtin_amdgcn_mfma_f32_32x32x16_bf16(a, wfr[ks], acc0, 0, 0, 0);
        else         acc1 = __builtin_amdgcn_mfma_f32_32x32x16_bf16(a, wfr[ks], acc1, 0, 0, 0);
      }
    }
  }

  // ---- relation loop: no barriers ----
#pragma unroll 1
  for (int r = 0; r < R_; ++r) {
    const int segLen = eSeg - sSeg;
    const int eN = (r < R_ - 1) ? __builtin_amdgcn_readlane(relEnd, r + 1) : eSeg;
    const u32 evN = srt[eSeg + lane];          // descriptors for relation r+1

    if (segLen > 0) {
      const u16* wr = wp + (size_t)((r * 4 + w) * 8) * 64 * 8;
      short8 wfr[8];
#pragma unroll
      for (int ks = 0; ks < 8; ++ks)
        wfr[ks] = *(const short8*)(wr + ((size_t)ks * 64 + lane) * 8);

      const int nChunks = (segLen + 31) >> 5;
#pragma unroll 1
      for (int c = 0; c < nChunks; ++c) {
        if (c > 0) {                            // rare multi-chunk path
          if ((c & 1) == 0) {                   // refresh 64-edge window
            ev = srt[sSeg + (c >> 1) * 64 + lane];
            tlv = (int)((ev >> 16) & 63);
            int L = r * 64 + tlv;
            int cE = offs[keyBase + L];
            int cS = (L > 0) ? offs[keyBase + L - 1] : 0;
            normu = (lane < segLen - (c >> 1) * 64) ? (u32)f2bf(1.0f / (float)(cE - cS)) : 0u;
          }
          u32 srn = (u32)__shfl((int)ev, ((c & 1) << 5) + l31) & 0xFFFFu;
          const u16* xp = xb + (size_t)srn * 128 + lh * 8;
#pragma unroll
          for (int ks = 0; ks < 8; ++ks) A0[ks] = *(const short8*)(xp + ks * 16);
        }

        // ---- P build: zero 64x40 tile + scatter 1/cnt at [tl][edge] ----
#pragma unroll
        for (int k = 0; k < 5; ++k)
          *(short8*)(myP + (size_t)lane * 40 + k * 8) = zero8;
        if ((lane >> 5) == (c & 1))
          myP[(size_t)tlv * 40 + l31] = (u16)normu;

        // ---- Z-GEMM: Z[32 edges x 32 cols] = Xg @ W[:, ct=w] ----
        f32x16 Z;
#pragma unroll
        for (int k = 0; k < 16; ++k) Z[k] = 0.f;
#pragma unroll
        for (int ks = 0; ks < 8; ++ks)
          Z = __builtin_amdgcn_mfma_f32_32x32x16_bf16(A0[ks], wfr[ks], Z, 0, 0, 0);

        // ---- Zt: C-layout -> [col][edge] bf16 (wave-private) ----
#pragma unroll
        for (int q = 0; q < 4; ++q) {
          u32 lo = pk2(Z[4 * q + 0], Z[4 * q + 1]);
          u32 hi = pk2(Z[4 * q + 2], Z[4 * q + 3]);
          *(uint2*)(myZt + (size_t)l31 * 40 + 8 * q + 4 * lh) = make_uint2(lo, hi);
        }

        // ---- acc += P[64x32] @ Z[32x32] ----
#pragma unroll
        for (int ks2 = 0; ks2 < 2; ++ks2) {
          short8 pf0 = *(const short8*)(myP + (size_t)l31 * 40 + ks2 * 16 + lh * 8);
          short8 pf1 = *(const short8*)(myP + (size_t)(32 + l31) * 40 + ks2 * 16 + lh * 8);
          short8 bz  = *(const short8*)(myZt + (size_t)l31 * 40 + ks2 * 16 + lh * 8);
          acc0 = __builtin_amdgcn_mfma_f32_32x32x16_bf16(pf0, bz, acc0, 0, 0, 0);
          acc1 = __builtin_amdgcn_mfma_f32_32x32x16_bf16(pf1, bz, acc1, 0, 0, 0);
        }
      }
    }

    // rotate to relation r+1: descriptors + (tl,norm) + chunk-0 A-gathers
    if (r < R_ - 1) {
      sSeg = eSeg; eSeg = eN;
      ev = evN;
      tlv = (int)((ev >> 16) & 63);
      int L = (r + 1) * 64 + tlv;
      int cE = offs[keyBase + L];
      int cS = offs[keyBase + L - 1];           // L >= 64 > 0 always
      normu = (lane < eSeg - sSeg) ? (u32)f2bf(1.0f / (float)(cE - cS)) : 0u;
      u32 srn = (u32)__shfl((int)ev, l31) & 0xFFFFu;
      const u16* xp = xb + (size_t)srn * 128 + lh * 8;
#pragma unroll
      for (int ks = 0; ks < 8; ++ks) A0[ks] = *(const short8*)(xp + ks * 16);
    }
  }

  // ---- epilogue: direct stores of this wave's columns + bias + relu ----
  const float bv = bias[w * 32 + l31];
#pragma unroll
  for (int mt = 0; mt < 2; ++mt) {
    const f32x16 a = mt ? acc1 : acc0;
#pragma unroll
    for (int q = 0; q < 4; ++q)
#pragma unroll
      for (int j = 0; j < 4; ++j) {
        const int row = nb + mt * 32 + 8 * q + 4 * lh + j;
        if (row < N) {
          float v = a[4 * q + j] + bv;
          h[(size_t)row * 128 + w * 32 + l31] = v > 0.f ? v : 0.f;
        }
      }
  }
}

// ---- DistMult scoring: one wave per triplet, float2 loads ----
__global__ void k_score(const float* __restrict__ h, const float* __restrict__ rel_emb,
                        const int* __restrict__ head, const int* __restrict__ tail,
                        const int* __restrict__ rel, float* __restrict__ out, int T) {
  int lane = threadIdx.x & 63, w = threadIdx.x >> 6;
  int gid = blockIdx.x * 4 + w;
  if (gid >= T) return;
  const float2 h2 = *(const float2*)(h + (size_t)head[gid] * 128 + 2 * lane);
  const float2 t2 = *(const float2*)(h + (size_t)tail[gid] * 128 + 2 * lane);
  const float2 r2 = *(const float2*)(rel_emb + (size_t)rel[gid] * 128 + 2 * lane);
  float s = h2.x * r2.x * t2.x + h2.y * r2.y * t2.y;
#pragma unroll
  for (int off = 32; off > 0; off >>= 1) s += __shfl_down(s, off);
  if (lane == 0) out[gid] = s;
}

extern "C" void kernel_launch(void* const* d_in, const int* in_sizes, int n_in,
                              void* d_out, int out_size, void* d_ws, size_t ws_size,
                              hipStream_t stream) {
  const float* x     = (const float*)d_in[0];
  const float* W     = (const float*)d_in[1];
  const float* Wroot = (const float*)d_in[2];
  const float* bias  = (const float*)d_in[3];
  const float* relE  = (const float*)d_in[4];
  const int* ei      = (const int*)d_in[5];
  const int* et      = (const int*)d_in[6];
  const int* headI   = (const int*)d_in[7];
  const int* tailI   = (const int*)d_in[8];
  const int* relI    = (const int*)d_in[9];
  float* out = (float*)d_out;

  const int N = in_sizes[0] / 128;   // 50000
  const int E = in_sizes[6];         // 600000
  const int T = in_sizes[7];         // 8192
  const int NB = (N + 63) >> 6;      // 782
  const int NKEYS = NB * KEYS_PER_B;

  char* p = (char*)d_ws;
  auto alloc = [&](size_t bytes) -> void* {
    void* r = (void*)p;
    p += (bytes + 255) & ~(size_t)255;
    return r;
  };
  u16* xb     = (u16*)alloc((size_t)N * 128 * 2);            // 12.8 MB
  u16* wp     = (u16*)alloc((size_t)33 * 2048 * 8 * 2);      // 1.08 MB (rel 32 = root)
  int* hist   = (int*)alloc((size_t)NKEYS * 4);              // 6.4 MB
  int* offs   = (int*)alloc((size_t)NKEYS * 4);              // 6.4 MB
  u32* sorted = (u32*)alloc(((size_t)NB * SORT_STRIDE + 64) * 4);
  float* h    = (float*)alloc((size_t)N * 128 * 4);          // 25.6 MB

  const int n4 = N * 128 / 4;
  const int convNB = (n4 + 255) / 256;
  const int packNB = (33 * 2048 + 255) / 256;
  const int histNB = (E / 4 + 255) / 256;

  hipMemsetAsync(hist, 0, (size_t)NKEYS * 4, stream);
  k_pre<<<convNB + packNB + histNB, 256, 0, stream>>>(x, W, Wroot, ei, et, xb, wp,
                                                      hist, n4, E, convNB, packNB);
  k_scan_local<<<NB, 256, 0, stream>>>(hist, offs);
  k_scatter<<<(E / 4 + 255) / 256, 256, 0, stream>>>(ei, et, offs, sorted, E);
  k_batch<<<NB, 256, 0, stream>>>(xb, wp, bias, sorted, offs, h, N);
  k_score<<<(T + 3) / 4, 256, 0, stream>>>(h, relE, headI, tailI, relI, out, T);
}